// Round 2
// baseline (763.347 us; speedup 1.0000x reference)
//
#include <hip/hip_runtime.h>
#include <hip/hip_bf16.h>
#include <math.h>

#define NVEC 65536
#define CD   256
#define KCODES 512
#define HW   1024
#define CHW  (CD * HW)          // 262144 elements per batch image
#define NQ   16777216           // q_st element count (64*256*32*32)

// ---- numpy pairwise_sum replica (8-accumulator blocks of 128, squares) ----
// numpy: r[j]=a[j]; for i=8..120 step 8: r[j]+=a[i+j];
//        res = ((r0+r1)+(r2+r3)) + ((r4+r5)+(r6+r7))
// squares are rounded first (x**2 is a separate ufunc), so __fmul_rn then
// __fadd_rn — both non-contractible, preserving numpy's exact fp32 bits.
__device__ __forceinline__ float fsq(float a) { return __fmul_rn(a, a); }

__device__ float pw128_sq(const float* __restrict__ p, int stride) {
    float r[8];
#pragma unroll
    for (int j = 0; j < 8; ++j) r[j] = fsq(p[j * stride]);
#pragma unroll
    for (int i = 8; i < 128; i += 8) {
#pragma unroll
        for (int j = 0; j < 8; ++j)
            r[j] = __fadd_rn(r[j], fsq(p[(i + j) * stride]));
    }
    return __fadd_rn(
        __fadd_rn(__fadd_rn(r[0], r[1]), __fadd_rn(r[2], r[3])),
        __fadd_rn(__fadd_rn(r[4], r[5]), __fadd_rn(r[6], r[7])));
}

// ---- e2[k] = numpy-pairwise sum of emb[k][:]**2 ----
extern "C" __global__ void vq_e2(const float* __restrict__ emb,
                                 float* __restrict__ e2g) {
    int k = blockIdx.x * blockDim.x + threadIdx.x;
    if (k < KCODES) {
        const float* p = emb + (size_t)k * CD;
        e2g[k] = __fadd_rn(pw128_sq(p, 1), pw128_sq(p + 128, 1));
    }
}

// ---- main: per-block 64 vectors, all 512 codes in 8 chunks of 64 ----
extern "C" __global__ __launch_bounds__(256, 1)
void vq_main(const float* __restrict__ x, const float* __restrict__ emb,
             const float* __restrict__ e2g, float* __restrict__ out,
             double* __restrict__ lacc) {
    __shared__ float xs[CD][64];   // 64 KB  x tile, [c][n]
    __shared__ float es[CD][64];   // 64 KB  emb chunk, [c][k]
    __shared__ float Sv[64];       // numpy-pairwise row sums
    __shared__ float rd[16][64];   // argmin reduction: d
    __shared__ int   rk[16][64];   // argmin reduction: k
    __shared__ int   kfin[64];

    const int t   = threadIdx.x;
    const int n0  = blockIdx.x << 6;       // 64 vectors per block
    const int b   = n0 >> 10;              // 64 | 1024 so block stays in one b
    const int hw0 = n0 & 1023;
    const float* xb = x + (size_t)b * CHW + hw0;   // xb[c*HW + nl]

    // stage x tile: thread owns 4 consecutive n (float4), 16 c-rows
    {
        const int nq = (t & 15) << 2;
        const int cr = t >> 4;             // 0..15
#pragma unroll
        for (int i = 0; i < 16; ++i) {
            const int c = cr + (i << 4);
            const float4 v = *reinterpret_cast<const float4*>(xb + (size_t)c * HW + nq);
            xs[c][nq + 0] = v.x; xs[c][nq + 1] = v.y;
            xs[c][nq + 2] = v.z; xs[c][nq + 3] = v.w;
        }
    }
    __syncthreads();
    if (t < 64) {
        // S[n], bitwise numpy pairwise (two 128-blocks, then one add)
        Sv[t] = __fadd_rn(pw128_sq(&xs[0][t], 64), pw128_sq(&xs[128][t], 64));
    }
    __syncthreads();

    const int tn4 = (t & 15) << 2;   // 4 n's per thread
    const int tk4 = (t >> 4) << 2;   // 4 k's per thread (within chunk)
    float bestd[4];
    int   bestk[4];
#pragma unroll
    for (int i = 0; i < 4; ++i) { bestd[i] = INFINITY; bestk[i] = 0; }

    for (int kc = 0; kc < 8; ++kc) {
        // stage emb chunk transposed: es[c][kl], kl = code within chunk
        {
            const int kl = t & 63;
            const int cg = t >> 6;         // 0..3
            const float* er = emb + (size_t)((kc << 6) + kl) * CD;
#pragma unroll
            for (int jj = 0; jj < 16; ++jj) {
                const int c = (cg << 6) + (jj << 2);
                const float4 v = *reinterpret_cast<const float4*>(er + c);
                es[c + 0][kl] = v.x; es[c + 1][kl] = v.y;
                es[c + 2][kl] = v.z; es[c + 3][kl] = v.w;
            }
        }
        __syncthreads();

        double acc[4][4];
#pragma unroll
        for (int i = 0; i < 4; ++i)
#pragma unroll
            for (int j = 0; j < 4; ++j) acc[i][j] = 0.0;

#pragma unroll 2
        for (int c = 0; c < CD; ++c) {
            float xv[4], ev[4];
#pragma unroll
            for (int i = 0; i < 4; ++i) xv[i] = xs[c][tn4 + i];
#pragma unroll
            for (int j = 0; j < 4; ++j) ev[j] = es[c][tk4 + j];
#pragma unroll
            for (int i = 0; i < 4; ++i)
#pragma unroll
                for (int j = 0; j < 4; ++j)
                    acc[i][j] = fma((double)xv[i], (double)ev[j], acc[i][j]);
        }

        // epilogue: mimic numpy fp32 rounding cascade, running argmin
#pragma unroll
        for (int i = 0; i < 4; ++i) {
            const float S = Sv[tn4 + i];
#pragma unroll
            for (int j = 0; j < 4; ++j) {
                const int k = (kc << 6) + tk4 + j;
                const float A  = __fadd_rn(S, e2g[k]);           // fl(S + e2)
                const float dw = 2.0f * (float)acc[i][j];        // exact *2 of rounded dot
                const float dd = __fsub_rn(A, dw);               // fl(A - 2dot)
                if (dd < bestd[i]) { bestd[i] = dd; bestk[i] = k; }  // k ascending per thread
            }
        }
        __syncthreads();
    }

    // cross-thread argmin reduction (16 k-groups per n), tie -> lower k
    {
        const int tkg = t >> 4;
#pragma unroll
        for (int i = 0; i < 4; ++i) { rd[tkg][tn4 + i] = bestd[i]; rk[tkg][tn4 + i] = bestk[i]; }
    }
    __syncthreads();
    if (t < 64) {
        float bd = rd[0][t];
        int   bk = rk[0][t];
#pragma unroll
        for (int g = 1; g < 16; ++g) {
            const float d2 = rd[g][t];
            const int   k2 = rk[g][t];
            if (d2 < bd || (d2 == bd && k2 < bk)) { bd = d2; bk = k2; }
        }
        kfin[t] = bk;
        out[(size_t)(NQ + 2) + n0 + t] = (float)bk;   // indices chunk, exact fp32
    }
    __syncthreads();

    // write q_st (NCHW fp32, coalesced over n) + loss accumulation
    {
        const int nl  = t & 63;
        const int cg  = t >> 6;
        const int myk = kfin[nl];
        const float* er = emb + (size_t)myk * CD;
        float* qb = out + (size_t)b * CHW + hw0 + nl;
        double ls = 0.0;
#pragma unroll 4
        for (int i = 0; i < 64; ++i) {
            const int c = (cg << 6) + i;
            const float e  = er[c];
            const float xv = xs[c][nl];
            const float df = e - xv;
            ls = fma((double)df, (double)df, ls);
            qb[(size_t)c * HW] = e;
        }
#pragma unroll
        for (int off = 32; off > 0; off >>= 1) ls += __shfl_down(ls, off);
        if ((t & 63) == 0) atomicAdd(lacc, ls);
    }
}

extern "C" __global__ void vq_fin(const double* __restrict__ lacc,
                                  float* __restrict__ out) {
    const float m = (float)(lacc[0] * (1.0 / (double)NQ));
    out[NQ]     = m;   // dictionary_loss
    out[NQ + 1] = m;   // commitment_loss (same forward value)
}

extern "C" void kernel_launch(void* const* d_in, const int* in_sizes, int n_in,
                              void* d_out, int out_size, void* d_ws, size_t ws_size,
                              hipStream_t stream) {
    const float* x   = (const float*)d_in[0];
    const float* emb = (const float*)d_in[1];
    float* out = (float*)d_out;
    double* lacc = (double*)d_ws;
    float*  e2g  = (float*)((char*)d_ws + 16);

    hipMemsetAsync(d_ws, 0, 16, stream);                     // zero loss accumulator
    vq_e2<<<2, 256, 0, stream>>>(emb, e2g);
    vq_main<<<NVEC / 64, 256, 0, stream>>>(x, emb, e2g, out, lacc);
    vq_fin<<<1, 1, 0, stream>>>(lacc, out);
}

// Round 3
// 752.562 us; speedup vs baseline: 1.0143x; 1.0143x over previous
//
#include <hip/hip_runtime.h>
#include <hip/hip_bf16.h>
#include <math.h>

#define NVEC 65536
#define CD   256
#define KCODES 512
#define HW   1024
#define CHW  (CD * HW)          // 262144 elements per batch image
#define NQ   16777216           // q_st element count (64*256*32*32)

// ---- numpy pairwise_sum replica (8-accumulator blocks of 128, squares) ----
__device__ __forceinline__ float fsq(float a) { return __fmul_rn(a, a); }

__device__ float pw128_sq(const float* __restrict__ p, int stride) {
    float r[8];
#pragma unroll
    for (int j = 0; j < 8; ++j) r[j] = fsq(p[j * stride]);
#pragma unroll
    for (int i = 8; i < 128; i += 8) {
#pragma unroll
        for (int j = 0; j < 8; ++j)
            r[j] = __fadd_rn(r[j], fsq(p[(i + j) * stride]));
    }
    return __fadd_rn(
        __fadd_rn(__fadd_rn(r[0], r[1]), __fadd_rn(r[2], r[3])),
        __fadd_rn(__fadd_rn(r[4], r[5]), __fadd_rn(r[6], r[7])));
}

// ---- e2[k] = numpy-pairwise sum of emb[k][:]**2 ----
extern "C" __global__ void vq_e2(const float* __restrict__ emb,
                                 float* __restrict__ e2g) {
    int k = blockIdx.x * blockDim.x + threadIdx.x;
    if (k < KCODES) {
        const float* p = emb + (size_t)k * CD;
        e2g[k] = __fadd_rn(pw128_sq(p, 1), pw128_sq(p + 128, 1));
    }
}

// ---- main: 512 threads (2 waves/SIMD), 64 vectors/block, 8 chunks of 64 ----
extern "C" __global__ __launch_bounds__(512, 2)
void vq_main(const float* __restrict__ x, const float* __restrict__ emb,
             const float* __restrict__ e2g, float* __restrict__ out,
             double* __restrict__ lacc) {
    __shared__ float xs[CD][64];   // 64 KB  x tile, [c][n]
    __shared__ float es[CD][64];   // 64 KB  emb chunk, [c][k]
    __shared__ float e2s[KCODES];  // 2 KB   code norms
    __shared__ float Sv[64];       // numpy-pairwise row sums
    __shared__ float rd[16][64];   // argmin reduction: d
    __shared__ int   rk[16][64];   // argmin reduction: k
    __shared__ int   kfin[64];

    const int t   = threadIdx.x;
    const int n0  = blockIdx.x << 6;       // 64 vectors per block
    const int b   = n0 >> 10;              // 64 | 1024: block stays in one b
    const int hw0 = n0 & 1023;
    const float* xb = x + (size_t)b * CHW + hw0;

    // ---- stage x tile: thread owns 4 consecutive n (float4), 8 c-rows ----
    {
        const int nq = (t & 15) << 2;
        const int cr = t >> 4;             // 0..31
#pragma unroll
        for (int i = 0; i < 8; ++i) {
            const int c = cr + (i << 5);
            const float4 v = *reinterpret_cast<const float4*>(xb + (size_t)c * HW + nq);
            *reinterpret_cast<float4*>(&xs[c][nq]) = v;
        }
    }
    if (t < KCODES) e2s[t] = e2g[t];
    __syncthreads();

    if (t < 64) {
        // S[n], bitwise numpy pairwise (two 128-blocks, then one add)
        Sv[t] = __fadd_rn(pw128_sq(&xs[0][t], 64), pw128_sq(&xs[128][t], 64));
    }

    // ---- emb chunk staging machinery (reg-staged, T14 split) ----
    const int kl = t & 63;                 // code row within chunk
    const int cg = t >> 6;                 // 0..7 -> 32-c slab
    float4 pf[8];
    {
        const float* er = emb + (size_t)kl * CD + (cg << 5);
#pragma unroll
        for (int j = 0; j < 8; ++j)
            pf[j] = *reinterpret_cast<const float4*>(er + (j << 2));
#pragma unroll
        for (int j = 0; j < 8; ++j) {
            const int c = (cg << 5) + (j << 2);
            es[c + 0][kl] = pf[j].x; es[c + 1][kl] = pf[j].y;
            es[c + 2][kl] = pf[j].z; es[c + 3][kl] = pf[j].w;
        }
    }

    const int ng2 = (t & 31) << 1;   // 2 n's per thread
    const int kg4 = (t >> 5) << 2;   // 4 k's per thread (within chunk)
    float bestd[2];
    int   bestk[2];
#pragma unroll
    for (int i = 0; i < 2; ++i) { bestd[i] = INFINITY; bestk[i] = 0; }

    for (int kc = 0; kc < 8; ++kc) {
        __syncthreads();               // es chunk kc (and Sv on kc=0) visible

        // prefetch next chunk into regs; pin issue before the compute loop
        if (kc < 7) {
            const float* er = emb + (size_t)(((kc + 1) << 6) + kl) * CD + (cg << 5);
#pragma unroll
            for (int j = 0; j < 8; ++j)
                pf[j] = *reinterpret_cast<const float4*>(er + (j << 2));
            __builtin_amdgcn_sched_barrier(0);
        }

        double acc[2][4];
#pragma unroll
        for (int i = 0; i < 2; ++i)
#pragma unroll
            for (int j = 0; j < 4; ++j) acc[i][j] = 0.0;

#pragma unroll 4
        for (int c = 0; c < CD; ++c) {
            float xv[2], ev[4];
            *reinterpret_cast<float2*>(xv) = *reinterpret_cast<const float2*>(&xs[c][ng2]);
            *reinterpret_cast<float4*>(ev) = *reinterpret_cast<const float4*>(&es[c][kg4]);
#pragma unroll
            for (int i = 0; i < 2; ++i)
#pragma unroll
                for (int j = 0; j < 4; ++j)
                    acc[i][j] = fma((double)xv[i], (double)ev[j], acc[i][j]);
        }

        // epilogue: numpy fp32 rounding cascade, running argmin
#pragma unroll
        for (int i = 0; i < 2; ++i) {
            const float S = Sv[ng2 + i];
#pragma unroll
            for (int j = 0; j < 4; ++j) {
                const int k = (kc << 6) + kg4 + j;
                const float A  = __fadd_rn(S, e2s[k]);           // fl(S + e2)
                const float dw = 2.0f * (float)acc[i][j];        // exact *2 of rounded dot
                const float dd = __fsub_rn(A, dw);               // fl(A - 2dot)
                if (dd < bestd[i]) { bestd[i] = dd; bestk[i] = k; }
            }
        }
        __syncthreads();               // all reads of es done

        if (kc < 7) {                  // write prefetched chunk kc+1
#pragma unroll
            for (int j = 0; j < 8; ++j) {
                const int c = (cg << 5) + (j << 2);
                es[c + 0][kl] = pf[j].x; es[c + 1][kl] = pf[j].y;
                es[c + 2][kl] = pf[j].z; es[c + 3][kl] = pf[j].w;
            }
        }
    }

    // ---- cross-thread argmin reduction (16 k-groups per n), tie -> lower k
    {
        const int tkg = t >> 5;
#pragma unroll
        for (int i = 0; i < 2; ++i) { rd[tkg][ng2 + i] = bestd[i]; rk[tkg][ng2 + i] = bestk[i]; }
    }
    __syncthreads();
    if (t < 64) {
        float bd = rd[0][t];
        int   bk = rk[0][t];
#pragma unroll
        for (int g = 1; g < 16; ++g) {
            const float d2 = rd[g][t];
            const int   k2 = rk[g][t];
            if (d2 < bd || (d2 == bd && k2 < bk)) { bd = d2; bk = k2; }
        }
        kfin[t] = bk;
        out[(size_t)(NQ + 2) + n0 + t] = (float)bk;   // indices chunk, exact fp32
    }
    __syncthreads();

    // ---- write q_st (NCHW fp32, coalesced over n) + loss accumulation ----
    {
        const int nl  = t & 63;
        const int myk = kfin[nl];
        const float* er = emb + (size_t)myk * CD;
        float* qb = out + (size_t)b * CHW + hw0 + nl;
        double ls = 0.0;
#pragma unroll 4
        for (int i = 0; i < 32; ++i) {
            const int c = (cg << 5) + i;
            const float e  = er[c];
            const float xv = xs[c][nl];
            const float df = e - xv;
            ls = fma((double)df, (double)df, ls);
            qb[(size_t)c * HW] = e;
        }
#pragma unroll
        for (int off = 32; off > 0; off >>= 1) ls += __shfl_down(ls, off);
        if ((t & 63) == 0) atomicAdd(lacc, ls);
    }
}

extern "C" __global__ void vq_fin(const double* __restrict__ lacc,
                                  float* __restrict__ out) {
    const float m = (float)(lacc[0] * (1.0 / (double)NQ));
    out[NQ]     = m;   // dictionary_loss
    out[NQ + 1] = m;   // commitment_loss (same forward value)
}

extern "C" void kernel_launch(void* const* d_in, const int* in_sizes, int n_in,
                              void* d_out, int out_size, void* d_ws, size_t ws_size,
                              hipStream_t stream) {
    const float* x   = (const float*)d_in[0];
    const float* emb = (const float*)d_in[1];
    float* out = (float*)d_out;
    double* lacc = (double*)d_ws;
    float*  e2g  = (float*)((char*)d_ws + 16);

    hipMemsetAsync(d_ws, 0, 16, stream);                     // zero loss accumulator
    vq_e2<<<2, 256, 0, stream>>>(emb, e2g);
    vq_main<<<NVEC / 64, 512, 0, stream>>>(x, emb, e2g, out, lacc);
    vq_fin<<<1, 1, 0, stream>>>(lacc, out);
}

// Round 4
// 309.768 us; speedup vs baseline: 2.4643x; 2.4294x over previous
//
#include <hip/hip_runtime.h>
#include <hip/hip_bf16.h>
#include <math.h>

#define NVEC 65536
#define CD   256
#define KCODES 512
#define HW   1024
#define CHW  (CD * HW)
#define NQ   16777216
#define MARGIN 3.0e-4f
#define CANDCAP 256

typedef __attribute__((ext_vector_type(8)))  short bf16x8;
typedef __attribute__((ext_vector_type(16))) float f32x16;
typedef unsigned long long u64;
typedef unsigned int u32;

union FragU { uint4 q; bf16x8 f; };

// deterministic RNE f32->bf16 split (no API ambiguity)
__device__ __forceinline__ unsigned short f2bf(float f) {
    unsigned u = __float_as_uint(f);
    return (unsigned short)((u + 0x7fffu + ((u >> 16) & 1u)) >> 16);
}
__device__ __forceinline__ float bf2f(unsigned short h) {
    return __uint_as_float((unsigned)h << 16);
}

__device__ __forceinline__ u64 sx64(u64 v, int m) {
    unsigned lo = __shfl_xor((unsigned)v, m);
    unsigned hi = __shfl_xor((unsigned)(v >> 32), m);
    return ((u64)hi << 32) | lo;
}

// exact numpy-cascade approx-dd (identical codegen in both uses)
__device__ __forceinline__ float dd_approx(float S, float e2, float d) {
    return __fsub_rn(__fadd_rn(S, e2), __fmul_rn(2.0f, d));
}

// ---- numpy pairwise_sum replica (8-acc blocks of 128, squares) ----
__device__ __forceinline__ float fsq(float a) { return __fmul_rn(a, a); }

__device__ float pw128_sq(const float* __restrict__ p, int stride) {
    float r[8];
#pragma unroll
    for (int j = 0; j < 8; ++j) r[j] = fsq(p[j * stride]);
#pragma unroll
    for (int i = 8; i < 128; i += 8) {
#pragma unroll
        for (int j = 0; j < 8; ++j)
            r[j] = __fadd_rn(r[j], fsq(p[(i + j) * stride]));
    }
    return __fadd_rn(
        __fadd_rn(__fadd_rn(r[0], r[1]), __fadd_rn(r[2], r[3])),
        __fadd_rn(__fadd_rn(r[4], r[5]), __fadd_rn(r[6], r[7])));
}

extern "C" __global__ void vq_e2(const float* __restrict__ emb,
                                 float* __restrict__ e2g) {
    int k = blockIdx.x * blockDim.x + threadIdx.x;
    if (k < KCODES) {
        const float* p = emb + (size_t)k * CD;
        e2g[k] = __fadd_rn(pw128_sq(p, 1), pw128_sq(p + 128, 1));
    }
}

// ---- e-frag precompute: B-frag-major bf16 limbs: [ct 16][ks 32][lane 64] x 16B
//      lane holds col=code=lane&31, k-octet group = lane>>5; ks 0..15 = e0, 16..31 = e1
extern "C" __global__ __launch_bounds__(256)
void vq_efrag(const float* __restrict__ emb, uint4* __restrict__ efrag) {
    __shared__ float es[32][257];
    const int t = threadIdx.x, ct = blockIdx.x;
    for (int i = t; i < 32 * 256; i += 256)
        es[i >> 8][i & 255] = emb[(size_t)ct * 32 * 256 + i];
    __syncthreads();
    const int code = t & 31, og = t >> 5;          // og 0..7
#pragma unroll
    for (int oo = 0; oo < 4; ++oo) {
        const int o = og * 4 + oo;                 // c-octet 0..31
        unsigned short h0[8], h1[8];
#pragma unroll
        for (int j = 0; j < 8; ++j) {
            float ev = es[code][o * 8 + j];
            unsigned short b0 = f2bf(ev);
            float r = ev - bf2f(b0);
            h0[j] = b0; h1[j] = f2bf(r);
        }
        const int lf = code + ((o & 1) << 5), ks = o >> 1;
        efrag[((size_t)ct * 32 + ks) * 64 + lf]      = *reinterpret_cast<uint4*>(h0);
        efrag[((size_t)ct * 32 + 16 + ks) * 64 + lf] = *reinterpret_cast<uint4*>(h1);
    }
}

// ---- main ----
extern "C" __global__ __launch_bounds__(256, 1)
void vq_main(const float* __restrict__ x, const float* __restrict__ emb,
             const float* __restrict__ e2g, const uint4* __restrict__ efrag,
             float* __restrict__ out, double* __restrict__ lacc) {
    __shared__ float xs[CD][64];          // 64 KB raw x tile [c][n]
    __shared__ uint4 xlf[2 * 32 * 64];    // 64 KB x-frag limbs [mt][ks][lane]
    __shared__ float Sh[2][64];
    __shared__ float Sv[64];
    __shared__ float e2s[KCODES];
    __shared__ u64   wt[4][64][2];        // per-wave top-2 per n
    __shared__ float dd1s[64];
    __shared__ int   flags[64];
    __shared__ int   kfin[64];
    __shared__ int   candn[CANDCAP], candk[CANDCAP];
    __shared__ u64   candres[CANDCAP];
    __shared__ int   cnt;

    const int t    = threadIdx.x;
    const int lane = t & 63;
    const int w    = t >> 6;              // wave 0..3
    const int n0   = blockIdx.x << 6;
    const int b    = n0 >> 10;
    const int hw0  = n0 & 1023;
    const float* xb = x + (size_t)b * CHW + hw0;

    // P0: stage raw x tile (coalesced float4 over n)
    {
        const int nq = (t & 15) << 2;
        const int cr = t >> 4;
#pragma unroll
        for (int i = 0; i < 16; ++i) {
            const int c = cr + (i << 4);
            *reinterpret_cast<float4*>(&xs[c][nq]) =
                *reinterpret_cast<const float4*>(xb + (size_t)c * HW + nq);
        }
    }
    for (int i = t; i < KCODES; i += 256) e2s[i] = e2g[i];
    __syncthreads();

    // P1a: numpy-pairwise half-sums
    if (t < 128) {
        const int n = t & 63, h = t >> 6;
        Sh[h][n] = pw128_sq(&xs[h * 128][0] + n, 64);
    }
    // P2: convert x -> frag-major bf16 limbs in LDS
    {
        const int n = t & 63, og = t >> 6;           // og 0..3
#pragma unroll
        for (int oo = 0; oo < 8; ++oo) {
            const int o = og * 8 + oo;               // c-octet 0..31
            unsigned short h0[8], h1[8];
#pragma unroll
            for (int j = 0; j < 8; ++j) {
                float xv = xs[o * 8 + j][n];
                unsigned short b0 = f2bf(xv);
                float r = xv - bf2f(b0);
                h0[j] = b0; h1[j] = f2bf(r);
            }
            const int mt = n >> 5, lf = (n & 31) + ((o & 1) << 5), ks = o >> 1;
            xlf[(mt * 32 + ks) * 64 + lf]      = *reinterpret_cast<uint4*>(h0);
            xlf[(mt * 32 + 16 + ks) * 64 + lf] = *reinterpret_cast<uint4*>(h1);
        }
    }
    __syncthreads();
    if (t < 64) Sv[t] = __fadd_rn(Sh[0][t], Sh[1][t]);
    if (t == 0) cnt = 0;
    __syncthreads();

    // P3: MFMA main loop. D[m=n][col=code], wave w covers codetiles w*4..w*4+3
    const int kt0 = w * 4;
    f32x16 acc[2][4];
#pragma unroll
    for (int mt = 0; mt < 2; ++mt)
#pragma unroll
        for (int j = 0; j < 4; ++j)
#pragma unroll
            for (int e = 0; e < 16; ++e) acc[mt][j][e] = 0.0f;

#pragma unroll
    for (int p = 0; p < 3; ++p) {
        const int aks0 = (p == 1) ? 16 : 0;   // x1 on pass 1
        const int bks0 = (p == 2) ? 16 : 0;   // e1 on pass 2
#pragma unroll 4
        for (int s = 0; s < 16; ++s) {
            FragU a0, a1, bq[4];
            a0.q = xlf[(0 * 32 + aks0 + s) * 64 + lane];
            a1.q = xlf[(1 * 32 + aks0 + s) * 64 + lane];
#pragma unroll
            for (int j = 0; j < 4; ++j)
                bq[j].q = efrag[((size_t)(kt0 + j) * 32 + bks0 + s) * 64 + lane];
#pragma unroll
            for (int j = 0; j < 4; ++j) {
                acc[0][j] = __builtin_amdgcn_mfma_f32_32x32x16_bf16(a0.f, bq[j].f, acc[0][j], 0, 0, 0);
                acc[1][j] = __builtin_amdgcn_mfma_f32_32x32x16_bf16(a1.f, bq[j].f, acc[1][j], 0, 0, 0);
            }
        }
    }

    // P4: per-wave top-2 per n (u64 pack: dd_bits<<32 | code -> min = min-dd-then-min-k)
#pragma unroll
    for (int mt = 0; mt < 2; ++mt) {
#pragma unroll
        for (int reg = 0; reg < 16; ++reg) {
            const int row = (reg & 3) + 8 * (reg >> 2) + 4 * (lane >> 5);
            const int n   = mt * 32 + row;
            const float S = Sv[n];
            u64 t1 = ~0ull, t2 = ~0ull;
#pragma unroll
            for (int j = 0; j < 4; ++j) {
                const int code = (kt0 + j) * 32 + (lane & 31);
                const float dd = dd_approx(S, e2s[code], acc[mt][j][reg]);
                u64 u = ((u64)__float_as_uint(dd) << 32) | (u32)code;
                if (u < t1) { t2 = t1; t1 = u; } else if (u < t2) t2 = u;
            }
#pragma unroll
            for (int d = 1; d < 32; d <<= 1) {
                u64 o1 = sx64(t1, d), o2 = sx64(t2, d);
                if (o1 < t1) { u64 tmp = t1; t1 = o1; o1 = tmp; }
                t2 = (o1 < t2) ? o1 : t2;
                t2 = (o2 < t2) ? o2 : t2;
            }
            if ((lane & 31) == 0) { wt[w][n][0] = t1; wt[w][n][1] = t2; }
        }
    }
    __syncthreads();

    // combine 4 waves -> final approx top-2, flag, loss
    if (t < 64) {
        u64 b1 = ~0ull, b2 = ~0ull;
#pragma unroll
        for (int wv = 0; wv < 4; ++wv) {
            u64 o1 = wt[wv][t][0], o2 = wt[wv][t][1];
            if (o1 < b1) { u64 tmp = b1; b1 = o1; o1 = tmp; }
            b2 = (o1 < b2) ? o1 : b2;
            b2 = (o2 < b2) ? o2 : b2;
        }
        const float dd1 = __uint_as_float((u32)(b1 >> 32));
        const float dd2 = __uint_as_float((u32)(b2 >> 32));
        kfin[t]  = (int)(b1 & 0xffffffffu);
        dd1s[t]  = dd1;
        flags[t] = (dd2 - dd1 <= MARGIN) ? 1 : 0;
        double l = (double)dd1;                       // loss contribution
#pragma unroll
        for (int d = 1; d < 64; d <<= 1) l += __shfl_xor(l, d);
        if (t == 0) atomicAdd(lacc, l);
    }
    __syncthreads();

    // P5a: collect candidates for flagged rows from live accumulators
#pragma unroll
    for (int mt = 0; mt < 2; ++mt) {
#pragma unroll
        for (int reg = 0; reg < 16; ++reg) {
            const int row = (reg & 3) + 8 * (reg >> 2) + 4 * (lane >> 5);
            const int n   = mt * 32 + row;
            if (flags[n]) {
                const float S = Sv[n];
                const float lim = dd1s[n] + MARGIN;
#pragma unroll
                for (int j = 0; j < 4; ++j) {
                    const int code = (kt0 + j) * 32 + (lane & 31);
                    const float dd = dd_approx(S, e2s[code], acc[mt][j][reg]);
                    if (dd <= lim) {
                        int id = atomicAdd(&cnt, 1);
                        if (id < CANDCAP) { candn[id] = n; candk[id] = code; }
                    }
                }
            }
        }
    }
    __syncthreads();

    // P5b: exact fp64 dot + cascade per candidate (one wave per candidate)
    const int nc = (cnt < CANDCAP) ? cnt : CANDCAP;
    for (int ci = w; ci < nc; ci += 4) {
        const int n = candn[ci], code = candk[ci];
        const float4 ev = *reinterpret_cast<const float4*>(emb + (size_t)code * CD + lane * 4);
        double ps = 0.0;
#pragma unroll
        for (int j = 0; j < 4; ++j) {
            const float evj = (j == 0) ? ev.x : (j == 1) ? ev.y : (j == 2) ? ev.z : ev.w;
            ps = fma((double)xs[lane * 4 + j][n], (double)evj, ps);
        }
#pragma unroll
        for (int d = 1; d < 64; d <<= 1) ps += __shfl_xor(ps, d);
        if (lane == 0) {
            const float A  = __fadd_rn(Sv[n], e2s[code]);
            const float dw = 2.0f * (float)ps;
            const float dd = __fsub_rn(A, dw);
            candres[ci] = ((u64)__float_as_uint(dd) << 32) | (u32)code;
        }
    }
    __syncthreads();

    // final index per n
    if (t < 64) {
        int k = kfin[t];
        if (flags[t]) {
            u64 best = ~0ull;
            for (int ci = 0; ci < nc; ++ci)
                if (candn[ci] == t && candres[ci] < best) best = candres[ci];
            k = (int)(best & 0xffffffffu);
            kfin[t] = k;
        }
        out[(size_t)(NQ + 2) + n0 + t] = (float)k;
    }
    __syncthreads();

    // P6: q_st write (NCHW fp32, coalesced over n)
    {
        const int nl = t & 63, cg = t >> 6;
        const int myk = kfin[nl];
        const float* er = emb + (size_t)myk * CD;
        float* qb = out + (size_t)b * CHW + hw0 + nl;
#pragma unroll 4
        for (int i = 0; i < 64; ++i) {
            const int c = (cg << 6) + i;
            qb[(size_t)c * HW] = er[c];
        }
    }
}

extern "C" __global__ void vq_fin(const double* __restrict__ lacc,
                                  float* __restrict__ out) {
    const float m = (float)(lacc[0] * (1.0 / (double)NQ));
    out[NQ]     = m;
    out[NQ + 1] = m;
}

extern "C" void kernel_launch(void* const* d_in, const int* in_sizes, int n_in,
                              void* d_out, int out_size, void* d_ws, size_t ws_size,
                              hipStream_t stream) {
    const float* x   = (const float*)d_in[0];
    const float* emb = (const float*)d_in[1];
    float* out = (float*)d_out;
    double* lacc  = (double*)d_ws;
    float*  e2g   = (float*)((char*)d_ws + 16);
    uint4*  efrag = (uint4*)((char*)d_ws + 4096);   // 512 KB

    hipMemsetAsync(d_ws, 0, 16, stream);
    vq_e2<<<2, 256, 0, stream>>>(emb, e2g);
    vq_efrag<<<16, 256, 0, stream>>>(emb, efrag);
    vq_main<<<NVEC / 64, 256, 0, stream>>>(x, emb, e2g, efrag, out, lacc);
    vq_fin<<<1, 1, 0, stream>>>(lacc, out);
}

// Round 5
// 212.535 us; speedup vs baseline: 3.5916x; 1.4575x over previous
//
#include <hip/hip_runtime.h>
#include <hip/hip_bf16.h>
#include <math.h>

#define NVEC 65536
#define CD   256
#define KCODES 512
#define HW   1024
#define CHW  (CD * HW)
#define NQ   16777216
#define MARGIN 3.0e-4f
#define CANDCAP 256

typedef __attribute__((ext_vector_type(8)))  short bf16x8;
typedef __attribute__((ext_vector_type(16))) float f32x16;
typedef unsigned long long u64;
typedef unsigned int u32;

union FragU { uint4 q; bf16x8 f; };

// deterministic RNE f32->bf16 split
__device__ __forceinline__ unsigned short f2bf(float f) {
    unsigned u = __float_as_uint(f);
    return (unsigned short)((u + 0x7fffu + ((u >> 16) & 1u)) >> 16);
}
__device__ __forceinline__ float bf2f(unsigned short h) {
    return __uint_as_float((unsigned)h << 16);
}

__device__ __forceinline__ u64 sx64(u64 v, int m) {
    unsigned lo = __shfl_xor((unsigned)v, m);
    unsigned hi = __shfl_xor((unsigned)(v >> 32), m);
    return ((u64)hi << 32) | lo;
}

// exact numpy-cascade approx-dd
__device__ __forceinline__ float dd_approx(float S, float e2, float d) {
    return __fsub_rn(__fadd_rn(S, e2), __fmul_rn(2.0f, d));
}

// ---- numpy pairwise_sum replica (8-acc blocks of 128, squares) ----
__device__ __forceinline__ float fsq(float a) { return __fmul_rn(a, a); }

__device__ float pw128_sq(const float* __restrict__ p, int stride) {
    float r[8];
#pragma unroll
    for (int j = 0; j < 8; ++j) r[j] = fsq(p[j * stride]);
#pragma unroll
    for (int i = 8; i < 128; i += 8) {
#pragma unroll
        for (int j = 0; j < 8; ++j)
            r[j] = __fadd_rn(r[j], fsq(p[(i + j) * stride]));
    }
    return __fadd_rn(
        __fadd_rn(__fadd_rn(r[0], r[1]), __fadd_rn(r[2], r[3])),
        __fadd_rn(__fadd_rn(r[4], r[5]), __fadd_rn(r[6], r[7])));
}

// ---- e-frag precompute + e2 (fused): frag layout identical to round 4 ----
extern "C" __global__ __launch_bounds__(256)
void vq_efrag(const float* __restrict__ emb, uint4* __restrict__ efrag,
              float* __restrict__ e2g) {
    __shared__ float es[32][257];
    const int t = threadIdx.x, ct = blockIdx.x;
    for (int i = t; i < 32 * 256; i += 256)
        es[i >> 8][i & 255] = emb[(size_t)ct * 32 * 256 + i];
    __syncthreads();
    const int code = t & 31, og = t >> 5;
#pragma unroll
    for (int oo = 0; oo < 4; ++oo) {
        const int o = og * 4 + oo;
        unsigned short h0[8], h1[8];
#pragma unroll
        for (int j = 0; j < 8; ++j) {
            float ev = es[code][o * 8 + j];
            unsigned short b0 = f2bf(ev);
            h0[j] = b0; h1[j] = f2bf(ev - bf2f(b0));
        }
        const int lf = code + ((o & 1) << 5), ks = o >> 1;
        efrag[((size_t)ct * 32 + ks) * 64 + lf]      = *reinterpret_cast<uint4*>(h0);
        efrag[((size_t)ct * 32 + 16 + ks) * 64 + lf] = *reinterpret_cast<uint4*>(h1);
    }
    if (t < 32)
        e2g[ct * 32 + t] = __fadd_rn(pw128_sq(&es[t][0], 1), pw128_sq(&es[t][128], 1));
}

// ---- main: 64 n/block, single 64KB LDS buffer (raw -> in-place frags) ----
extern "C" __global__ __launch_bounds__(256, 2)
void vq_main(const float* __restrict__ x, const float* __restrict__ emb,
             const float* __restrict__ e2g, const uint4* __restrict__ efrag,
             float* __restrict__ out, double* __restrict__ lacc) {
    __shared__ float xraw[CD * 64];       // 64 KB: raw x [c][n], then xlf frags
    __shared__ float Sh[2][64];
    __shared__ float Sv[64];
    __shared__ float e2s[KCODES];
    __shared__ u64   wt[4][64][2];
    __shared__ float dd1s[64];
    __shared__ int   flags[64];
    __shared__ int   kfin[64];
    __shared__ int   candn[CANDCAP], candk[CANDCAP];
    __shared__ u64   candres[CANDCAP];
    __shared__ int   cnt;

    const int t    = threadIdx.x;
    const int lane = t & 63;
    const int w    = t >> 6;
    const int n0   = blockIdx.x << 6;
    const int b    = n0 >> 10;
    const int hw0  = n0 & 1023;
    const float* xb = x + (size_t)b * CHW + hw0;

    // P0: stage raw x tile (coalesced float4 over n)
    {
        const int nq = (t & 15) << 2;
        const int cr = t >> 4;
#pragma unroll
        for (int i = 0; i < 16; ++i) {
            const int c = cr + (i << 4);
            *reinterpret_cast<float4*>(&xraw[c * 64 + nq]) =
                *reinterpret_cast<const float4*>(xb + (size_t)c * HW + nq);
        }
    }
    for (int i = t; i < KCODES; i += 256) e2s[i] = e2g[i];
    if (t == 0) cnt = 0;
    __syncthreads();

    // P1: read frag sources + numpy-S columns into registers (no writes yet)
    const int lf  = t & 63;
    const int ksq = (t >> 6) << 2;        // ks base: 0/4/8/12
    float src[2][32];
#pragma unroll
    for (int mt = 0; mt < 2; ++mt) {
        const int n = (mt << 5) + (lf & 31);
#pragma unroll
        for (int q = 0; q < 4; ++q)
#pragma unroll
            for (int j = 0; j < 8; ++j) {
                const int c = (ksq + q) * 16 + ((lf >> 5) << 3) + j;
                src[mt][q * 8 + j] = xraw[c * 64 + n];
            }
    }
    float sh = 0.0f;
    if (t < 128) sh = pw128_sq(&xraw[(t >> 6) * 128 * 64 + (t & 63)], 64);
    __syncthreads();                       // all raw reads complete

    // P2: in-place conversion to bf16-limb frags (layout == round 4)
    uint4* xlf = reinterpret_cast<uint4*>(xraw);
#pragma unroll
    for (int mt = 0; mt < 2; ++mt)
#pragma unroll
        for (int q = 0; q < 4; ++q) {
            const int ks = ksq + q;
            unsigned short h0[8], h1[8];
#pragma unroll
            for (int j = 0; j < 8; ++j) {
                const float v = src[mt][q * 8 + j];
                unsigned short b0 = f2bf(v);
                h0[j] = b0; h1[j] = f2bf(v - bf2f(b0));
            }
            xlf[(mt * 32 + ks) * 64 + lf]      = *reinterpret_cast<uint4*>(h0);
            xlf[(mt * 32 + 16 + ks) * 64 + lf] = *reinterpret_cast<uint4*>(h1);
        }
    if (t < 128) Sh[t >> 6][t & 63] = sh;
    __syncthreads();
    if (t < 64) Sv[t] = __fadd_rn(Sh[0][t], Sh[1][t]);
    __syncthreads();

    // P3: MFMA main loop (fused limb schedule: e0 read once for x0,x1)
    const int kt0 = w * 4;
    f32x16 acc[2][4];
#pragma unroll
    for (int mt = 0; mt < 2; ++mt)
#pragma unroll
        for (int j = 0; j < 4; ++j)
#pragma unroll
            for (int e = 0; e < 16; ++e) acc[mt][j][e] = 0.0f;

#pragma unroll 4
    for (int s = 0; s < 16; ++s) {
        FragU a00, a10, a01, a11, b0[4], b1[4];
        a00.q = xlf[(0 * 32 + s) * 64 + lane];
        a10.q = xlf[(1 * 32 + s) * 64 + lane];
        a01.q = xlf[(0 * 32 + 16 + s) * 64 + lane];
        a11.q = xlf[(1 * 32 + 16 + s) * 64 + lane];
#pragma unroll
        for (int j = 0; j < 4; ++j) {
            b0[j].q = efrag[((size_t)(kt0 + j) * 32 + s) * 64 + lane];
            b1[j].q = efrag[((size_t)(kt0 + j) * 32 + 16 + s) * 64 + lane];
        }
#pragma unroll
        for (int j = 0; j < 4; ++j) {
            acc[0][j] = __builtin_amdgcn_mfma_f32_32x32x16_bf16(a00.f, b0[j].f, acc[0][j], 0, 0, 0);
            acc[1][j] = __builtin_amdgcn_mfma_f32_32x32x16_bf16(a10.f, b0[j].f, acc[1][j], 0, 0, 0);
            acc[0][j] = __builtin_amdgcn_mfma_f32_32x32x16_bf16(a01.f, b0[j].f, acc[0][j], 0, 0, 0);
            acc[1][j] = __builtin_amdgcn_mfma_f32_32x32x16_bf16(a11.f, b0[j].f, acc[1][j], 0, 0, 0);
            acc[0][j] = __builtin_amdgcn_mfma_f32_32x32x16_bf16(a00.f, b1[j].f, acc[0][j], 0, 0, 0);
            acc[1][j] = __builtin_amdgcn_mfma_f32_32x32x16_bf16(a10.f, b1[j].f, acc[1][j], 0, 0, 0);
        }
    }

    // P4: per-wave top-2 per n (u64 pack), butterfly over 32-lane groups
#pragma unroll
    for (int mt = 0; mt < 2; ++mt) {
#pragma unroll
        for (int reg = 0; reg < 16; ++reg) {
            const int row = (reg & 3) + 8 * (reg >> 2) + 4 * (lane >> 5);
            const int n   = mt * 32 + row;
            const float S = Sv[n];
            u64 t1 = ~0ull, t2 = ~0ull;
#pragma unroll
            for (int j = 0; j < 4; ++j) {
                const int code = (kt0 + j) * 32 + (lane & 31);
                const float dd = dd_approx(S, e2s[code], acc[mt][j][reg]);
                u64 u = ((u64)__float_as_uint(dd) << 32) | (u32)code;
                if (u < t1) { t2 = t1; t1 = u; } else if (u < t2) t2 = u;
            }
#pragma unroll
            for (int d = 1; d < 32; d <<= 1) {
                u64 o1 = sx64(t1, d), o2 = sx64(t2, d);
                if (o1 < t1) { u64 tmp = t1; t1 = o1; o1 = tmp; }
                t2 = (o1 < t2) ? o1 : t2;
                t2 = (o2 < t2) ? o2 : t2;
            }
            if ((lane & 31) == 0) { wt[w][n][0] = t1; wt[w][n][1] = t2; }
        }
    }
    __syncthreads();

    // combine 4 waves -> approx top-2, flag near-ties, loss
    if (t < 64) {
        u64 b1 = ~0ull, b2 = ~0ull;
#pragma unroll
        for (int wv = 0; wv < 4; ++wv) {
            u64 o1 = wt[wv][t][0], o2 = wt[wv][t][1];
            if (o1 < b1) { u64 tmp = b1; b1 = o1; o1 = tmp; }
            b2 = (o1 < b2) ? o1 : b2;
            b2 = (o2 < b2) ? o2 : b2;
        }
        const float dd1 = __uint_as_float((u32)(b1 >> 32));
        const float dd2 = __uint_as_float((u32)(b2 >> 32));
        kfin[t]  = (int)(b1 & 0xffffffffu);
        dd1s[t]  = dd1;
        flags[t] = (dd2 - dd1 <= MARGIN) ? 1 : 0;
        double l = (double)dd1;
#pragma unroll
        for (int d = 1; d < 64; d <<= 1) l += __shfl_xor(l, d);
        if (t == 0) atomicAdd(lacc, l);
    }
    __syncthreads();

    // P5a: collect candidates for flagged rows
#pragma unroll
    for (int mt = 0; mt < 2; ++mt) {
#pragma unroll
        for (int reg = 0; reg < 16; ++reg) {
            const int row = (reg & 3) + 8 * (reg >> 2) + 4 * (lane >> 5);
            const int n   = mt * 32 + row;
            if (flags[n]) {
                const float S = Sv[n];
                const float lim = dd1s[n] + MARGIN;
#pragma unroll
                for (int j = 0; j < 4; ++j) {
                    const int code = (kt0 + j) * 32 + (lane & 31);
                    const float dd = dd_approx(S, e2s[code], acc[mt][j][reg]);
                    if (dd <= lim) {
                        int id = atomicAdd(&cnt, 1);
                        if (id < CANDCAP) { candn[id] = n; candk[id] = code; }
                    }
                }
            }
        }
    }
    __syncthreads();

    // P5b: exact fp64 dot + cascade per candidate (x re-read from global/L3)
    const int nc = (cnt < CANDCAP) ? cnt : CANDCAP;
    for (int ci = w; ci < nc; ci += 4) {
        const int n = candn[ci], code = candk[ci];
        const float4 ev = *reinterpret_cast<const float4*>(emb + (size_t)code * CD + lane * 4);
        const float* xcol = xb + n;
        double ps = 0.0;
#pragma unroll
        for (int j = 0; j < 4; ++j) {
            const float evj = (j == 0) ? ev.x : (j == 1) ? ev.y : (j == 2) ? ev.z : ev.w;
            ps = fma((double)xcol[(size_t)(lane * 4 + j) * HW], (double)evj, ps);
        }
#pragma unroll
        for (int d = 1; d < 64; d <<= 1) ps += __shfl_xor(ps, d);
        if (lane == 0) {
            const float A  = __fadd_rn(Sv[n], e2s[code]);
            const float dw = 2.0f * (float)ps;
            const float dd = __fsub_rn(A, dw);
            candres[ci] = ((u64)__float_as_uint(dd) << 32) | (u32)code;
        }
    }
    __syncthreads();

    // final index per n
    if (t < 64) {
        int k = kfin[t];
        if (flags[t]) {
            u64 best = ~0ull;
            for (int ci = 0; ci < nc; ++ci)
                if (candn[ci] == t && candres[ci] < best) best = candres[ci];
            k = (int)(best & 0xffffffffu);
            kfin[t] = k;
        }
        out[(size_t)(NQ + 2) + n0 + t] = (float)k;
    }
    __syncthreads();

    // P6: q_st write (NCHW fp32, coalesced over n)
    {
        const int nl = t & 63, cg = t >> 6;
        const int myk = kfin[nl];
        const float* er = emb + (size_t)myk * CD;
        float* qb = out + (size_t)b * CHW + hw0 + nl;
#pragma unroll 4
        for (int i = 0; i < 64; ++i) {
            const int c = (cg << 6) + i;
            qb[(size_t)c * HW] = er[c];
        }
    }
}

extern "C" __global__ void vq_fin(const double* __restrict__ lacc,
                                  float* __restrict__ out) {
    const float m = (float)(lacc[0] * (1.0 / (double)NQ));
    out[NQ]     = m;
    out[NQ + 1] = m;
}

extern "C" void kernel_launch(void* const* d_in, const int* in_sizes, int n_in,
                              void* d_out, int out_size, void* d_ws, size_t ws_size,
                              hipStream_t stream) {
    const float* x   = (const float*)d_in[0];
    const float* emb = (const float*)d_in[1];
    float* out = (float*)d_out;
    double* lacc  = (double*)d_ws;
    float*  e2g   = (float*)((char*)d_ws + 16);
    uint4*  efrag = (uint4*)((char*)d_ws + 4096);   // 512 KB

    hipMemsetAsync(d_ws, 0, 16, stream);
    vq_efrag<<<16, 256, 0, stream>>>(emb, efrag, e2g);
    vq_main<<<NVEC / 64, 256, 0, stream>>>(x, emb, e2g, efrag, out, lacc);
    vq_fin<<<1, 1, 0, stream>>>(lacc, out);
}